// Round 15
// baseline (183.421 us; speedup 1.0000x reference)
//
#include <hip/hip_runtime.h>
#include <cstdint>
#include <cstddef>

// Problem constants
#define B_    2
#define S_    1024
#define DM_   2048
#define H_    16
#define HKV_  8
#define D_    128
#define W_    256
#define NPROJ 8192
#define MROWS 2048
#define SCALE_ 0.08838834764831845f
#define MNEG  -3.0e38f
#define FIXM  16.0f   // fixed softmax shift: |q.k|*SCALE <= 12.8 < 16 by RMSNorm construction

typedef float  f32x4  __attribute__((ext_vector_type(4)));
typedef __bf16 bf16x8 __attribute__((ext_vector_type(8)));
typedef __bf16 bf16x4 __attribute__((ext_vector_type(4)));

// ---------------------------------------------------------------- helpers
__device__ __forceinline__ void gload16(const void* g, void* l) {
  __builtin_amdgcn_global_load_lds((const __attribute__((address_space(1))) unsigned int*)g,
                                   (__attribute__((address_space(3))) unsigned int*)l, 16, 0, 0);
}

// ---------------------------------------------------------------- fused f32 -> bf16 convert + bias concat
__global__ __launch_bounds__(256) void cvt_all(
    const float* __restrict__ x,  const float* __restrict__ wq,  const float* __restrict__ wk,
    const float* __restrict__ wv, const float* __restrict__ wq2, const float* __restrict__ wk2,
    const float* __restrict__ wv2,const float* __restrict__ wo,
    const float* __restrict__ bq, const float* __restrict__ bk, const float* __restrict__ bv,
    const float* __restrict__ bq2,const float* __restrict__ bk2,const float* __restrict__ bv2,
    __bf16* __restrict__ xb, __bf16* __restrict__ wall, __bf16* __restrict__ wob,
    float* __restrict__ biasA) {
  const int i = blockIdx.x * 256 + threadIdx.x;   // f32x4 group index
  if (i >= 6293504) return;
  if (i >= 6291456) {                              // bias concat: 8192 floats
    const int j = i - 6291456, flat = j * 4;
    const int set = flat >> 12, off = flat & 4095;
    const float* bsrc; int boff;
    if (off < 2048)      { bsrc = set ? bq2 : bq; boff = off; }
    else if (off < 3072) { bsrc = set ? bk2 : bk; boff = off - 2048; }
    else                 { bsrc = set ? bv2 : bv; boff = off - 3072; }
    ((f32x4*)biasA)[j] = *(const f32x4*)&bsrc[boff];
    return;
  }
  const float* s; __bf16* d;
  if      (i < 1048576) { s = x   + (size_t)i * 4;              d = xb   + (size_t)i * 4; }
  else if (i < 2097152) { s = wq  + (size_t)(i - 1048576) * 4;  d = wall + (size_t)(i - 1048576) * 4; }
  else if (i < 2621440) { s = wk  + (size_t)(i - 2097152) * 4;  d = wall + 4194304  + (size_t)(i - 2097152) * 4; }
  else if (i < 3145728) { s = wv  + (size_t)(i - 2621440) * 4;  d = wall + 6291456  + (size_t)(i - 2621440) * 4; }
  else if (i < 4194304) { s = wq2 + (size_t)(i - 3145728) * 4;  d = wall + 8388608  + (size_t)(i - 3145728) * 4; }
  else if (i < 4718592) { s = wk2 + (size_t)(i - 4194304) * 4;  d = wall + 12582912 + (size_t)(i - 4194304) * 4; }
  else if (i < 5242880) { s = wv2 + (size_t)(i - 4718592) * 4;  d = wall + 14680064 + (size_t)(i - 4718592) * 4; }
  else                  { s = wo  + (size_t)(i - 5242880) * 4;  d = wob  + (size_t)(i - 5242880) * 4; }
  float4 f = *(const float4*)s;
  bf16x4 o;
  o.x = (__bf16)f.x; o.y = (__bf16)f.y; o.z = (__bf16)f.z; o.w = (__bf16)f.w;
  *(bf16x4*)d = o;
}

// ---------------------------------------------------------------- QKV GEMM: 256x256, BK=32, 3-slot ring
// Barrier-minimal: ONE vmcnt + ONE barrier per K-slice. Slot s = j%3 (32KB: A[256][32]|B[256][32],
// 64B rows, rotation swizzle q=(g+(r>>1))&3, 2-way = free). Stage slot j+2 (4 gload16/thread) is
// issued BEFORE compute; boundary waits vmcnt(4): slot j+1's 4 loads (issued a full tile ago)
// retired, slot j+2's 4 stay in flight ACROSS the barrier (counted T4, no added barriers).
// Intra-tile barriers removed: waves only read slot j / write slot (j+2)%3 (disjoint regions);
// boundary barrier alone orders read-complete vs overwrite.
__global__ __launch_bounds__(512) void gemm_qkv(const __bf16* __restrict__ A,
                                                const __bf16* __restrict__ Bm,
                                                __bf16* __restrict__ Cv,
                                                const float* __restrict__ bias,
                                                int N, int K, int nxp) {
  __shared__ __align__(16) char lds[98304];   // 3 slots x 32KB
  const int tid = threadIdx.x, lane = tid & 63, wid = tid >> 6;
  const int bid = blockIdx.x, xcd = bid & 7, ii = bid >> 3;
  const int x = xcd * nxp + (ii % nxp);
  const int y = ii / nxp;
  const int m0 = y * 256, n0 = x * 256;
  const int wm = (wid >> 2) * 128, wn = (wid & 3) * 64;
  const int g = lane >> 4, c16 = lane & 15;

  // staging precompute: step st covers slot bytes [st*8192 + tid*16, +16)
  int sRow[4], sColE[4]; bool sA4[4];
#pragma unroll
  for (int st = 0; st < 4; ++st) {
    const int o = st * 8192 + tid * 16;
    sA4[st]  = o < 16384;
    sRow[st] = (o & 16383) >> 6;
    const int q = (o >> 4) & 3;
    sColE[st] = ((q - (sRow[st] >> 1)) & 3) << 3;   // pre-rotated logical col (elems)
  }

  auto stageTile = [&](int j) {
    const int s = j % 3;
#pragma unroll
    for (int st = 0; st < 4; ++st) {
      const __bf16* src = sA4[st] ? &A [(size_t)(m0 + sRow[st]) * K + j * 32 + sColE[st]]
                                  : &Bm[(size_t)(n0 + sRow[st]) * K + j * 32 + sColE[st]];
      gload16(src, lds + s * 32768 + st * 8192 + wid * 1024);
    }
  };
  auto rdA = [&](int s, int mi) -> bf16x8 {
    const int r = wm + mi * 16 + c16;
    const int q = (g + (r >> 1)) & 3;
    return *(const bf16x8*)(lds + s * 32768 + r * 64 + q * 16);
  };
  auto rdB = [&](int s, int ni) -> bf16x8 {
    const int r = wn + ni * 16 + c16;
    const int q = (g + (r >> 1)) & 3;
    return *(const bf16x8*)(lds + s * 32768 + 16384 + r * 64 + q * 16);
  };

  f32x4 acc[8][4] = {};
  const int NS = K >> 5;   // 64 K-slices

  // prologue: slots 0,1 in flight; wait for slot 0 only
  stageTile(0);
  stageTile(1);
  asm volatile("s_waitcnt vmcnt(4)" ::: "memory");
  __builtin_amdgcn_s_barrier();

  for (int j = 0; j < NS; ++j) {
    const int s = j % 3;
    if (j + 2 < NS) stageTile(j + 2);   // issue-early: 4 loads into slot (j+2)%3

    bf16x8 a[8], bfr[4];
#pragma unroll
    for (int mi = 0; mi < 8; ++mi) a[mi] = rdA(s, mi);
#pragma unroll
    for (int ni = 0; ni < 4; ++ni) bfr[ni] = rdB(s, ni);

    __builtin_amdgcn_s_setprio(1);
#pragma unroll
    for (int mi = 0; mi < 8; ++mi)
#pragma unroll
      for (int ni = 0; ni < 4; ++ni)
        acc[mi][ni] = __builtin_amdgcn_mfma_f32_16x16x32_bf16(a[mi], bfr[ni], acc[mi][ni], 0, 0, 0);
    __builtin_amdgcn_s_setprio(0);

    if (j + 1 < NS) {
      if (j + 2 < NS) { asm volatile("s_waitcnt vmcnt(4)" ::: "memory"); }  // slot j+1 landed; j+2 flies
      else            { asm volatile("s_waitcnt vmcnt(0)" ::: "memory"); }  // final drain
      __builtin_amdgcn_s_barrier();
    }
  }

#pragma unroll
  for (int mi = 0; mi < 8; ++mi)
#pragma unroll
    for (int ni = 0; ni < 4; ++ni) {
      const int gn = n0 + wn + ni * 16 + c16;
      const float bv = bias[gn];
#pragma unroll
      for (int r = 0; r < 4; ++r) {
        const int gm = m0 + wm + mi * 16 + g * 4 + r;
        Cv[(size_t)gm * N + gn] = (__bf16)(acc[mi][ni][r] + bv);
      }
    }
}

// ---------------------------------------------------------------- output GEMM: 128x128 tiles, f32 out (R13)
__global__ __launch_bounds__(256) void gemm_out(const __bf16* __restrict__ A,
                                                const __bf16* __restrict__ Bm,
                                                float* __restrict__ Cv) {
  __shared__ __align__(16) char lds[65536];    // [buf 32K][A 16K | B 16K]
  const int tid = threadIdx.x, lane = tid & 63, wid = tid >> 6;
  const int bid = blockIdx.x, xcd = bid & 7, ii = bid >> 3;
  const int x = xcd * 2 + (ii & 1);
  const int y = ii >> 1;
  const int m0 = y * 128, n0 = x * 128;
  const int wm = (wid >> 1) * 64, wn = (wid & 1) * 64;
  const int g = lane >> 4, c16 = lane & 15;
  const int K = DM_, N = DM_;

  const int tR = tid >> 3;                                     // row within 32-row chunk
  const int tC = (((tid & 7) * 16) ^ ((tR & 7) << 4)) >> 1;    // pre-swizzled col (elems)

  auto stageP = [&](int k0, int buf, int p) {
    const __bf16* src = (p < 4) ? &A [(size_t)(m0 + p * 32 + tR) * K + k0 + tC]
                                : &Bm[(size_t)(n0 + (p - 4) * 32 + tR) * K + k0 + tC];
    gload16(src, lds + buf * 32768 + p * 4096 + wid * 1024);
  };
  auto rdA = [&](int buf, int mi, int kk) -> bf16x8 {
    const int r = wm + mi * 16 + c16;
    return *(const bf16x8*)(lds + buf * 32768 + r * 128 + ((kk * 64 + g * 16) ^ ((r & 7) << 4)));
  };
  auto rdB = [&](int buf, int ni, int kk) -> bf16x8 {
    const int r = wn + ni * 16 + c16;
    return *(const bf16x8*)(lds + buf * 32768 + 16384 + r * 128 + ((kk * 64 + g * 16) ^ ((r & 7) << 4)));
  };

  f32x4 acc[4][4] = {};
  const int NT = K >> 6;    // 32

#pragma unroll
  for (int p = 0; p < 8; ++p) stageP(0, 0, p);
  asm volatile("s_waitcnt vmcnt(0)" ::: "memory");
  __builtin_amdgcn_s_barrier();

  for (int t = 0; t < NT; ++t) {
    const int buf = t & 1, k0 = t * 64;
    bf16x8 b[4][2];
#pragma unroll
    for (int q = 0; q < 4; ++q) {
      bf16x8 a[2];
#pragma unroll
      for (int kk = 0; kk < 2; ++kk) a[kk] = rdA(buf, q, kk);
      if (q == 0) {
#pragma unroll
        for (int ni = 0; ni < 4; ++ni)
#pragma unroll
          for (int kk = 0; kk < 2; ++kk) b[ni][kk] = rdB(buf, ni, kk);
      }
      if (t + 1 < NT) { stageP(k0 + 64, buf ^ 1, q * 2); stageP(k0 + 64, buf ^ 1, q * 2 + 1); }
      __builtin_amdgcn_s_barrier();
      __builtin_amdgcn_s_setprio(1);
#pragma unroll
      for (int ni = 0; ni < 4; ++ni)
#pragma unroll
        for (int kk = 0; kk < 2; ++kk)
          acc[q][ni] = __builtin_amdgcn_mfma_f32_16x16x32_bf16(a[kk], b[ni][kk], acc[q][ni], 0, 0, 0);
      __builtin_amdgcn_s_setprio(0);
    }
    if (t + 1 < NT) { asm volatile("s_waitcnt vmcnt(0)" ::: "memory"); }
    __builtin_amdgcn_s_barrier();
  }

#pragma unroll
  for (int mi = 0; mi < 4; ++mi)
#pragma unroll
    for (int ni = 0; ni < 4; ++ni) {
      const int gn = n0 + wn + ni * 16 + c16;
#pragma unroll
      for (int r = 0; r < 4; ++r) {
        const int gm = m0 + wm + mi * 16 + g * 4 + r;
        Cv[(size_t)gm * N + gn] = acc[mi][ni][r];
      }
    }
}

// ---------------------------------------------------------------- merged post: RMSNorm+RoPE Q/K  |  V^T
__global__ __launch_bounds__(256) void post_all(const __bf16* __restrict__ proj,
    const float* __restrict__ cosg, const float* __restrict__ sing,
    const float* __restrict__ gq, const float* __restrict__ gk,
    const float* __restrict__ gq2, const float* __restrict__ gk2,
    __bf16* __restrict__ Q0, __bf16* __restrict__ K0,
    __bf16* __restrict__ Q1, __bf16* __restrict__ K1,
    __bf16* __restrict__ Vt0, __bf16* __restrict__ Vt1) {
  __shared__ __bf16 T[64][136];
  const int tid = threadIdx.x;
  if (blockIdx.x < 2048) {
    const int row  = blockIdx.x;
    const int b    = row >> 10;
    const int s    = row & 1023;
    const int lane = tid & 63, wid = tid >> 6;
    const float* cp = cosg + (size_t)row * D_;
    const float* sp = sing + (size_t)row * D_;
    const float c1 = cp[lane], c2 = cp[lane + 64];
    const float s1 = sp[lane], s2 = sp[lane + 64];

    for (int hi = wid; hi < 48; hi += 4) {
      const int  set  = hi >= 24 ? 1 : 0;
      const int  loc  = hi - set * 24;
      const bool isq  = loc < 16;
      const int  head = isq ? loc : loc - 16;
      const __bf16* src = proj + (size_t)row * NPROJ + set * 4096 + (isq ? head * 128 : 2048 + head * 128);
      const float* gv   = set ? (isq ? gq2 : gk2) : (isq ? gq : gk);
      __bf16* dst       = set ? (isq ? Q1 : K1) : (isq ? Q0 : K0);
      const int nheads  = isq ? H_ : HKV_;
      const size_t didx = (((size_t)b * nheads + head) * S_ + s) * D_;
      float x1 = (float)src[lane], x2 = (float)src[lane + 64];
      float ss = x1 * x1 + x2 * x2;
#pragma unroll
      for (int o = 1; o < 64; o <<= 1) ss += __shfl_xor(ss, o);
      const float rr = rsqrtf(ss * (1.f / 128.f) + 1e-6f);
      const float n1 = x1 * rr * gv[lane];
      const float n2 = x2 * rr * gv[lane + 64];
      dst[didx + lane]      = (__bf16)(n1 * c1 - n2 * s1);
      dst[didx + lane + 64] = (__bf16)(n2 * c2 + n1 * s2);
    }
  } else {
    const int bid = blockIdx.x - 2048;
    const int st = bid & 15;
    const int hk = (bid >> 4) & 7;
    const int b  = (bid >> 7) & 1;
    const int sg = bid >> 8;
    const int s0 = st * 64;
    const size_t prow = ((size_t)(b * S_ + s0)) * NPROJ + sg * 4096 + 3072 + hk * 128;
    const int r = tid >> 4, c = (tid & 15) * 8;
#pragma unroll
    for (int pass = 0; pass < 4; ++pass) {
      const int rr = pass * 16 + r;
      *(bf16x8*)&T[rr][c] = *(const bf16x8*)&proj[prow + (size_t)rr * NPROJ + c];
    }
    __syncthreads();
    __bf16* Vt = (sg ? Vt1 : Vt0) + (size_t)(b * HKV_ + hk) * D_ * S_;
    const int d = tid >> 1, half = tid & 1;
#pragma unroll
    for (int q8 = 0; q8 < 4; ++q8) {
      const int sb = half * 32 + q8 * 8;
      bf16x8 v;
#pragma unroll
      for (int k = 0; k < 8; ++k) v[k] = T[sb + k][d];
      *(bf16x8*)&Vt[(size_t)d * S_ + s0 + sb] = v;
    }
  }
}

// ---------------------------------------------------------------- fused two-stream windowed attention
__global__ __launch_bounds__(256) void attn_fused(
    const __bf16* __restrict__ Q0, const __bf16* __restrict__ K0g, const __bf16* __restrict__ Vt0,
    const __bf16* __restrict__ Q1, const __bf16* __restrict__ K1g, const __bf16* __restrict__ Vt1,
    __bf16* __restrict__ AO) {
  __shared__ __bf16 KsL[2][2][32 * 128];
  __shared__ __bf16 VtL[2][2][128 * 32];
  __shared__ __bf16 Ps[4][16][40];

  const int tid = threadIdx.x, lane = tid & 63, wid = tid >> 6;
  const int bid = blockIdx.x;
  const int xcd = bid & 7, jj = bid >> 3;
  const int combo = xcd * 2 + (jj >> 4);
  const int b = combo >> 3, hk = combo & 7;
  const int h = hk * 2 + ((jj >> 3) & 1);
  const int pq = jj & 7;
  const int qtA = pq, qtB = 15 - pq;
  const int ntA = 2 * qtA + 2;
  const int ntT = 34;

  const int g = lane >> 4, kc = lane & 15;
  const size_t qoff  = (size_t)(b * H_ + h) * S_ * D_;
  const size_t koff  = (size_t)(b * HKV_ + hk) * S_ * D_;
  const size_t vtoff = (size_t)(b * HKV_ + hk) * D_ * S_;

  int kRow[2], kCol[2], vD[2], vJ[2];
#pragma unroll
  for (int p = 0; p < 2; ++p) {
    const int boff = (wid * 2 + p) * 1024 + lane * 16;
    kRow[p] = boff >> 8;
    kCol[p] = ((boff & 255) ^ ((kRow[p] & 7) << 4)) >> 1;
    vD[p]   = boff >> 6;
    vJ[p]   = (boff & 63) >> 1;
  }

  bf16x8 qf0[4], qf1[4];
  auto loadQ = [&](int qw) {
    const int qrow = qw + kc;
#pragma unroll
    for (int c = 0; c < 4; ++c) {
      qf0[c] = *(const bf16x8*)&Q0[qoff + (size_t)qrow * D_ + c * 32 + g * 8];
      qf1[c] = *(const bf16x8*)&Q1[qoff + (size_t)qrow * D_ + c * 32 + g * 8];
    }
  };

  float rs[4];
  f32x4 o[8];
  auto resetS = [&]() {
#pragma unroll
    for (int r = 0; r < 4; ++r) rs[r] = 0.f;
#pragma unroll
    for (int ch = 0; ch < 8; ++ch)
#pragma unroll
      for (int r = 0; r < 4; ++r) o[ch][r] = 0.f;
  };

  auto stage = [&](int qb2, int t, int bufi) {
    const int j0 = t * 32;
    const bool nic = (j0 >= qb2 - 286);
    const bool nf  = (j0 <= qb2 - 193);
#pragma unroll
    for (int p = 0; p < 2; ++p) {
      const int ko = wid * 2048 + p * 1024;
      if (nic) {
        gload16(K0g + koff + (size_t)(j0 + kRow[p]) * D_ + kCol[p], (char*)&KsL[bufi][0][0] + ko);
        gload16(Vt0 + vtoff + (size_t)vD[p] * S_ + j0 + vJ[p],      (char*)&VtL[bufi][0][0] + ko);
      }
      if (nf) {
        gload16(K1g + koff + (size_t)(j0 + kRow[p]) * D_ + kCol[p], (char*)&KsL[bufi][1][0] + ko);
        gload16(Vt1 + vtoff + (size_t)vD[p] * S_ + j0 + vJ[p],      (char*)&VtL[bufi][1][0] + ko);
      }
    }
  };

  auto qk = [&](const __bf16* Kb, const bf16x8 qf[4], f32x4 sv[2]) {
#pragma unroll
    for (int c = 0; c < 4; ++c) {
      const int r0 = kc, r1 = kc + 16;
      const bf16x8 k0f = *(const bf16x8*)((const char*)Kb + r0 * 256 + ((c * 64 + g * 16) ^ ((r0 & 7) << 4)));
      const bf16x8 k1f = *(const bf16x8*)((const char*)Kb + r1 * 256 + ((c * 64 + g * 16) ^ ((r1 & 7) << 4)));
      sv[0] = __builtin_amdgcn_mfma_f32_16x16x32_bf16(qf[c], k0f, sv[0], 0, 0, 0);
      sv[1] = __builtin_amdgcn_mfma_f32_16x16x32_bf16(qf[c], k1f, sv[1], 0, 0, 0);
    }
  };

  auto dopv = [&](const f32x4 sv[2], const __bf16* Vtb) {
#pragma unroll
    for (int nh = 0; nh < 2; ++nh) {
      const int col = kc + nh * 16, c8 = col >> 3, cw = col & 7;
#pragma unroll
      for (int r = 0; r < 4; ++r)
        Ps[wid][g * 4 + r][((c8 ^ g) << 3) + cw] = (__bf16)sv[nh][r];
    }
    asm volatile("s_waitcnt lgkmcnt(0)" ::: "memory");
    const bf16x8 pa = *(const bf16x8*)&Ps[wid][kc][(g ^ (kc >> 2)) << 3];
#pragma unroll
    for (int ch = 0; ch < 8; ++ch) {
      const bf16x8 vb = *(const bf16x8*)&Vtb[(ch * 16 + kc) * 32 + g * 8];
      o[ch] = __builtin_amdgcn_mfma_f32_16x16x32_bf16(pa, vb, o[ch], 0, 0, 0);
    }
  };

  auto writeOut = [&](int qw2) {
    float ell[4];
#pragma unroll
    for (int r = 0; r < 4; ++r) ell[r] = rs[r];
#pragma unroll
    for (int ofs = 1; ofs < 16; ofs <<= 1)
#pragma unroll
      for (int r = 0; r < 4; ++r) ell[r] += __shfl_xor(ell[r], ofs);
#pragma unroll
    for (int r = 0; r < 4; ++r) {
      const float inv = 1.f / ell[r];
      const size_t orow = ((size_t)b * S_ + qw2 + g * 4 + r) * (size_t)(H_ * D_) + h * D_;
#pragma unroll
      for (int ch = 0; ch < 8; ++ch)
        AO[orow + ch * 16 + kc] = (__bf16)(o[ch][r] * inv);
    }
  };

  int qb = qtA * 64, qw = qb + wid * 16;
  loadQ(qw);
  resetS();
  stage(qb, 0, 0);
  asm volatile("s_waitcnt vmcnt(0)" ::: "memory");
  __builtin_amdgcn_s_barrier();
  int cur = 0;

  for (int it = 0; it < ntT; ++it) {
    const int t = (it >= ntA) ? it - ntA : it;
    if (it + 1 < ntT) {
      const bool hN = (it + 1 >= ntA);
      stage(hN ? qtB * 64 : qtA * 64, hN ? it + 1 - ntA : it + 1, cur ^ 1);
    }
    const int j0 = t * 32;
    if (j0 <= qw + 15) {
      const bool w_ic = (j0 >= qw - 286);
      const bool w_f  = (j0 <= qw - 241);

      f32x4 sic[2] = {}, sfd[2] = {};
      if (w_ic) {
        qk(&KsL[cur][0][0], qf0, sic);
#pragma unroll
        for (int nh = 0; nh < 2; ++nh)
#pragma unroll
          for (int r = 0; r < 4; ++r) {
            const int dij = (qw + g * 4 + r) - (j0 + kc + nh * 16);
            const float arg = (dij >= 0 && dij < W_) ? fmaf(sic[nh][r], SCALE_, -FIXM) : MNEG;
            const float p = __expf(arg);
            rs[r] += p; sic[nh][r] = p;
          }
        dopv(sic, &VtL[cur][0][0]);
      }
      if (w_f) {
        qk(&KsL[cur][1][0], qf1, sfd);
#pragma unroll
        for (int nh = 0; nh < 2; ++nh)
#pragma unroll
          for (int r = 0; r < 4; ++r) {
            const int dij = (qw + g * 4 + r) - (j0 + kc + nh * 16);
            const float arg = (dij >= W_) ? fmaf(sfd[nh][r], SCALE_, -FIXM) : MNEG;
            const float p = __expf(arg);
            rs[r] += p; sfd[nh][r] = p;
          }
        dopv(sfd, &VtL[cur][1][0]);
      }
    }
    asm volatile("s_waitcnt vmcnt(0)" ::: "memory");
    __builtin_amdgcn_s_barrier();
    cur ^= 1;

    if (it + 1 == ntA) {
      writeOut(qw);
      resetS();
      qb = qtB * 64; qw = qb + wid * 16;
      loadQ(qw);
    }
  }
  writeOut(qw);
}

// ---------------------------------------------------------------- launch
extern "C" void kernel_launch(void* const* d_in, const int* in_sizes, int n_in,
                              void* d_out, int out_size, void* d_ws, size_t ws_size,
                              hipStream_t stream) {
  (void)in_sizes; (void)n_in; (void)out_size; (void)ws_size;
  const float* hidden = (const float*)d_in[0];
  const float* cosg   = (const float*)d_in[1];
  const float* sing   = (const float*)d_in[2];
  const float* Wq  = (const float*)d_in[3];
  const float* bq  = (const float*)d_in[4];
  const float* Wk  = (const float*)d_in[5];
  const float* bk  = (const float*)d_in[6];
  const float* Wv  = (const float*)d_in[7];
  const float* bv  = (const float*)d_in[8];
  const float* Wq2 = (const float*)d_in[9];
  const float* bq2 = (const float*)d_in[10];
  const float* Wk2 = (const float*)d_in[11];
  const float* bk2 = (const float*)d_in[12];
  const float* Wv2 = (const float*)d_in[13];
  const float* bv2 = (const float*)d_in[14];
  const float* Wo  = (const float*)d_in[15];
  const float* gq  = (const float*)d_in[16];
  const float* gk  = (const float*)d_in[17];
  const float* gq2 = (const float*)d_in[18];
  const float* gk2 = (const float*)d_in[19];

  // ws layout (bytes): [Xb 8M | Wall 32M | Wob 8M | bias 32K | proj 32M]
  char* w = (char*)d_ws;
  __bf16* Xb    = (__bf16*)(w);
  __bf16* Wall  = (__bf16*)(w + 8388608);
  __bf16* Wob   = (__bf16*)(w + 41943040);
  float*  biasA = (float*) (w + 50331648);
  __bf16* proj  = (__bf16*)(w + 50364416);
  // region reuse after gemm_qkv consumed Xb/Wall:
  __bf16* AO  = Xb;
  __bf16* Q0  = Wall;
  __bf16* Q1  = Wall + 4194304;
  __bf16* K0  = Wall + 8388608;
  __bf16* K1  = Wall + 10485760;
  __bf16* Vt0 = Wall + 12582912;
  __bf16* Vt1 = Wall + 14680064;

  cvt_all<<<24584, 256, 0, stream>>>(hidden, Wq, Wk, Wv, Wq2, Wk2, Wv2, Wo,
                                     bq, bk, bv, bq2, bk2, bv2,
                                     Xb, Wall, Wob, biasA);
  gemm_qkv<<<256, 512, 0, stream>>>(Xb, Wall, proj, biasA, NPROJ, DM_, 4);
  post_all<<<2560, 256, 0, stream>>>(proj, cosg, sing, gq, gk, gq2, gk2,
                                     Q0, K0, Q1, K1, Vt0, Vt1);
  attn_fused<<<256, 256, 0, stream>>>(Q0, K0, Vt0, Q1, K1, Vt1, AO);
  gemm_out<<<256, 256, 0, stream>>>(AO, Wob, (float*)d_out);
}

// Round 16
// 172.638 us; speedup vs baseline: 1.0625x; 1.0625x over previous
//
#include <hip/hip_runtime.h>
#include <cstdint>
#include <cstddef>

// Problem constants
#define B_    2
#define S_    1024
#define DM_   2048
#define H_    16
#define HKV_  8
#define D_    128
#define W_    256
#define NPROJ 8192
#define MROWS 2048
#define SCALE_ 0.08838834764831845f
#define MNEG  -3.0e38f
#define FIXM  16.0f   // fixed softmax shift: |q.k|*SCALE <= 12.8 < 16 by RMSNorm construction

typedef float  f32x4  __attribute__((ext_vector_type(4)));
typedef __bf16 bf16x8 __attribute__((ext_vector_type(8)));
typedef __bf16 bf16x4 __attribute__((ext_vector_type(4)));

// ---------------------------------------------------------------- helpers
__device__ __forceinline__ void gload16(const void* g, void* l) {
  __builtin_amdgcn_global_load_lds((const __attribute__((address_space(1))) unsigned int*)g,
                                   (__attribute__((address_space(3))) unsigned int*)l, 16, 0, 0);
}

// ---------------------------------------------------------------- fused f32 -> bf16 convert + bias concat
__global__ __launch_bounds__(256) void cvt_all(
    const float* __restrict__ x,  const float* __restrict__ wq,  const float* __restrict__ wk,
    const float* __restrict__ wv, const float* __restrict__ wq2, const float* __restrict__ wk2,
    const float* __restrict__ wv2,const float* __restrict__ wo,
    const float* __restrict__ bq, const float* __restrict__ bk, const float* __restrict__ bv,
    const float* __restrict__ bq2,const float* __restrict__ bk2,const float* __restrict__ bv2,
    __bf16* __restrict__ xb, __bf16* __restrict__ wall, __bf16* __restrict__ wob,
    float* __restrict__ biasA) {
  const int i = blockIdx.x * 256 + threadIdx.x;   // f32x4 group index
  if (i >= 6293504) return;
  if (i >= 6291456) {                              // bias concat: 8192 floats
    const int j = i - 6291456, flat = j * 4;
    const int set = flat >> 12, off = flat & 4095;
    const float* bsrc; int boff;
    if (off < 2048)      { bsrc = set ? bq2 : bq; boff = off; }
    else if (off < 3072) { bsrc = set ? bk2 : bk; boff = off - 2048; }
    else                 { bsrc = set ? bv2 : bv; boff = off - 3072; }
    ((f32x4*)biasA)[j] = *(const f32x4*)&bsrc[boff];
    return;
  }
  const float* s; __bf16* d;
  if      (i < 1048576) { s = x   + (size_t)i * 4;              d = xb   + (size_t)i * 4; }
  else if (i < 2097152) { s = wq  + (size_t)(i - 1048576) * 4;  d = wall + (size_t)(i - 1048576) * 4; }
  else if (i < 2621440) { s = wk  + (size_t)(i - 2097152) * 4;  d = wall + 4194304  + (size_t)(i - 2097152) * 4; }
  else if (i < 3145728) { s = wv  + (size_t)(i - 2621440) * 4;  d = wall + 6291456  + (size_t)(i - 2621440) * 4; }
  else if (i < 4194304) { s = wq2 + (size_t)(i - 3145728) * 4;  d = wall + 8388608  + (size_t)(i - 3145728) * 4; }
  else if (i < 4718592) { s = wk2 + (size_t)(i - 4194304) * 4;  d = wall + 12582912 + (size_t)(i - 4194304) * 4; }
  else if (i < 5242880) { s = wv2 + (size_t)(i - 4718592) * 4;  d = wall + 14680064 + (size_t)(i - 4718592) * 4; }
  else                  { s = wo  + (size_t)(i - 5242880) * 4;  d = wob  + (size_t)(i - 5242880) * 4; }
  float4 f = *(const float4*)s;
  bf16x4 o;
  o.x = (__bf16)f.x; o.y = (__bf16)f.y; o.z = (__bf16)f.z; o.w = (__bf16)f.w;
  *(bf16x4*)d = o;
}

// ---------------------------------------------------------------- QKV GEMM: 256x256 tiles, drain0 (R13 revert)
__global__ __launch_bounds__(512) void gemm_qkv(const __bf16* __restrict__ A,
                                                const __bf16* __restrict__ Bm,
                                                __bf16* __restrict__ Cv,
                                                const float* __restrict__ bias,
                                                int N, int K, int nxp) {
  __shared__ __align__(16) char lds[131072];   // [buf 64K][A 32K | B 32K]
  const int tid = threadIdx.x, lane = tid & 63, wid = tid >> 6;
  const int bid = blockIdx.x, xcd = bid & 7, ii = bid >> 3;
  const int x = xcd * nxp + (ii % nxp);
  const int y = ii / nxp;
  const int m0 = y * 256, n0 = x * 256;
  const int wm = (wid >> 2) * 128, wn = (wid & 3) * 64;
  const int g = lane >> 4, c16 = lane & 15;

  int sRow[8], sCol[8]; bool sA[8];
#pragma unroll
  for (int p = 0; p < 8; ++p) {
    const int o = p * 8192 + tid * 16, ro = o & 32767;
    sA[p]   = o < 32768;
    sRow[p] = ro >> 7;
    sCol[p] = (((ro & 127) ^ ((sRow[p] & 7) << 4))) >> 1;
  }

  auto stage2 = [&](int k0, int buf, int q) {
#pragma unroll
    for (int pp = 0; pp < 2; ++pp) {
      const int p = q * 2 + pp;
      const __bf16* src = sA[p] ? &A [(size_t)(m0 + sRow[p]) * K + k0 + sCol[p]]
                                : &Bm[(size_t)(n0 + sRow[p]) * K + k0 + sCol[p]];
      gload16(src, lds + buf * 65536 + p * 8192 + wid * 1024);
    }
  };
  auto rdA = [&](int buf, int mi, int kk) -> bf16x8 {
    const int r = wm + mi * 16 + c16;
    return *(const bf16x8*)(lds + buf * 65536 + r * 128 + ((kk * 64 + g * 16) ^ ((r & 7) << 4)));
  };
  auto rdB = [&](int buf, int ni, int kk) -> bf16x8 {
    const int r = wn + ni * 16 + c16;
    return *(const bf16x8*)(lds + buf * 65536 + 32768 + r * 128 + ((kk * 64 + g * 16) ^ ((r & 7) << 4)));
  };

  f32x4 acc[8][4] = {};
  const int NT = K >> 6;

#pragma unroll
  for (int q = 0; q < 4; ++q) stage2(0, 0, q);
  asm volatile("s_waitcnt vmcnt(0)" ::: "memory");
  __builtin_amdgcn_s_barrier();

  for (int t = 0; t < NT; ++t) {
    const int buf = t & 1, k0 = t * 64;
    bf16x8 b[4][2];
#pragma unroll
    for (int q = 0; q < 4; ++q) {
      bf16x8 a[2][2];
#pragma unroll
      for (int dm = 0; dm < 2; ++dm)
#pragma unroll
        for (int kk = 0; kk < 2; ++kk) a[dm][kk] = rdA(buf, q * 2 + dm, kk);
      if (q == 0) {
#pragma unroll
        for (int ni = 0; ni < 4; ++ni)
#pragma unroll
          for (int kk = 0; kk < 2; ++kk) b[ni][kk] = rdB(buf, ni, kk);
      }
      if (t + 1 < NT) stage2(k0 + 64, buf ^ 1, q);
      __builtin_amdgcn_s_barrier();
      __builtin_amdgcn_s_setprio(1);
#pragma unroll
      for (int dm = 0; dm < 2; ++dm)
#pragma unroll
        for (int ni = 0; ni < 4; ++ni)
#pragma unroll
          for (int kk = 0; kk < 2; ++kk)
            acc[q * 2 + dm][ni] =
              __builtin_amdgcn_mfma_f32_16x16x32_bf16(a[dm][kk], b[ni][kk], acc[q * 2 + dm][ni], 0, 0, 0);
      __builtin_amdgcn_s_setprio(0);
    }
    if (t + 1 < NT) { asm volatile("s_waitcnt vmcnt(0)" ::: "memory"); }
    __builtin_amdgcn_s_barrier();
  }

#pragma unroll
  for (int mi = 0; mi < 8; ++mi)
#pragma unroll
    for (int ni = 0; ni < 4; ++ni) {
      const int gn = n0 + wn + ni * 16 + c16;
      const float bv = bias[gn];
#pragma unroll
      for (int r = 0; r < 4; ++r) {
        const int gm = m0 + wm + mi * 16 + g * 4 + r;
        Cv[(size_t)gm * N + gn] = (__bf16)(acc[mi][ni][r] + bv);
      }
    }
}

// ---------------------------------------------------------------- output GEMM: 128x128 tiles, 8 WAVES (2/SIMD)
// 512 thr as 2x4 waves, per-wave 64x32 (acc[4][2]); BK=64, 64KB LDS dbuf, drain0+XOR swizzle.
__global__ __launch_bounds__(512) void gemm_out(const __bf16* __restrict__ A,
                                                const __bf16* __restrict__ Bm,
                                                float* __restrict__ Cv) {
  __shared__ __align__(16) char lds[65536];    // [buf 32K][A 16K | B 16K]
  const int tid = threadIdx.x, lane = tid & 63, wid = tid >> 6;
  const int bid = blockIdx.x, xcd = bid & 7, ii = bid >> 3;
  const int x = xcd * 2 + (ii & 1);
  const int y = ii >> 1;
  const int m0 = y * 128, n0 = x * 128;
  const int wm = (wid >> 2) * 64, wn = (wid & 3) * 32;
  const int g = lane >> 4, c16 = lane & 15;
  const int K = DM_, N = DM_;

  const int tR = tid >> 3;                                     // 0..63 row within 64-row chunk
  const int tC = (((tid & 7) * 16) ^ ((tR & 7) << 4)) >> 1;    // pre-swizzled col (elems)

  auto stageP = [&](int k0, int buf, int p) {
    // p 0,1 -> A rows [p*64..); p 2,3 -> B rows [(p-2)*64..)
    const __bf16* src = (p < 2) ? &A [(size_t)(m0 + p * 64 + tR) * K + k0 + tC]
                                : &Bm[(size_t)(n0 + (p - 2) * 64 + tR) * K + k0 + tC];
    gload16(src, lds + buf * 32768 + p * 8192 + wid * 1024);
  };
  auto rdA = [&](int buf, int mi, int kk) -> bf16x8 {
    const int r = wm + mi * 16 + c16;
    return *(const bf16x8*)(lds + buf * 32768 + r * 128 + ((kk * 64 + g * 16) ^ ((r & 7) << 4)));
  };
  auto rdB = [&](int buf, int ni, int kk) -> bf16x8 {
    const int r = wn + ni * 16 + c16;
    return *(const bf16x8*)(lds + buf * 32768 + 16384 + r * 128 + ((kk * 64 + g * 16) ^ ((r & 7) << 4)));
  };

  f32x4 acc[4][2] = {};
  const int NT = K >> 6;    // 32

#pragma unroll
  for (int p = 0; p < 4; ++p) stageP(0, 0, p);
  asm volatile("s_waitcnt vmcnt(0)" ::: "memory");
  __builtin_amdgcn_s_barrier();

  for (int t = 0; t < NT; ++t) {
    const int buf = t & 1, k0 = t * 64;
    const bool more = (t + 1 < NT);
    bf16x8 b[2][2], a[2][2];

    // ---- phase 0: mi 0,1 ----
#pragma unroll
    for (int dm = 0; dm < 2; ++dm)
#pragma unroll
      for (int kk = 0; kk < 2; ++kk) a[dm][kk] = rdA(buf, dm, kk);
#pragma unroll
    for (int ni = 0; ni < 2; ++ni)
#pragma unroll
      for (int kk = 0; kk < 2; ++kk) b[ni][kk] = rdB(buf, ni, kk);
    if (more) { stageP(k0 + 64, buf ^ 1, 0); stageP(k0 + 64, buf ^ 1, 1); }
    __builtin_amdgcn_s_barrier();
    __builtin_amdgcn_s_setprio(1);
#pragma unroll
    for (int dm = 0; dm < 2; ++dm)
#pragma unroll
      for (int ni = 0; ni < 2; ++ni)
#pragma unroll
        for (int kk = 0; kk < 2; ++kk)
          acc[dm][ni] = __builtin_amdgcn_mfma_f32_16x16x32_bf16(a[dm][kk], b[ni][kk], acc[dm][ni], 0, 0, 0);
    __builtin_amdgcn_s_setprio(0);

    // ---- phase 1: mi 2,3 ----
#pragma unroll
    for (int dm = 0; dm < 2; ++dm)
#pragma unroll
      for (int kk = 0; kk < 2; ++kk) a[dm][kk] = rdA(buf, 2 + dm, kk);
    if (more) { stageP(k0 + 64, buf ^ 1, 2); stageP(k0 + 64, buf ^ 1, 3); }
    __builtin_amdgcn_s_barrier();
    __builtin_amdgcn_s_setprio(1);
#pragma unroll
    for (int dm = 0; dm < 2; ++dm)
#pragma unroll
      for (int ni = 0; ni < 2; ++ni)
#pragma unroll
        for (int kk = 0; kk < 2; ++kk)
          acc[2 + dm][ni] = __builtin_amdgcn_mfma_f32_16x16x32_bf16(a[dm][kk], b[ni][kk], acc[2 + dm][ni], 0, 0, 0);
    __builtin_amdgcn_s_setprio(0);

    if (more) { asm volatile("s_waitcnt vmcnt(0)" ::: "memory"); }
    __builtin_amdgcn_s_barrier();
  }

#pragma unroll
  for (int mi = 0; mi < 4; ++mi)
#pragma unroll
    for (int ni = 0; ni < 2; ++ni) {
      const int gn = n0 + wn + ni * 16 + c16;
#pragma unroll
      for (int r = 0; r < 4; ++r) {
        const int gm = m0 + wm + mi * 16 + g * 4 + r;
        Cv[(size_t)gm * N + gn] = acc[mi][ni][r];
      }
    }
}

// ---------------------------------------------------------------- merged post: RMSNorm+RoPE Q/K  |  V^T
__global__ __launch_bounds__(256) void post_all(const __bf16* __restrict__ proj,
    const float* __restrict__ cosg, const float* __restrict__ sing,
    const float* __restrict__ gq, const float* __restrict__ gk,
    const float* __restrict__ gq2, const float* __restrict__ gk2,
    __bf16* __restrict__ Q0, __bf16* __restrict__ K0,
    __bf16* __restrict__ Q1, __bf16* __restrict__ K1,
    __bf16* __restrict__ Vt0, __bf16* __restrict__ Vt1) {
  __shared__ __bf16 T[64][136];
  const int tid = threadIdx.x;
  if (blockIdx.x < 2048) {
    const int row  = blockIdx.x;
    const int b    = row >> 10;
    const int s    = row & 1023;
    const int lane = tid & 63, wid = tid >> 6;
    const float* cp = cosg + (size_t)row * D_;
    const float* sp = sing + (size_t)row * D_;
    const float c1 = cp[lane], c2 = cp[lane + 64];
    const float s1 = sp[lane], s2 = sp[lane + 64];

    for (int hi = wid; hi < 48; hi += 4) {
      const int  set  = hi >= 24 ? 1 : 0;
      const int  loc  = hi - set * 24;
      const bool isq  = loc < 16;
      const int  head = isq ? loc : loc - 16;
      const __bf16* src = proj + (size_t)row * NPROJ + set * 4096 + (isq ? head * 128 : 2048 + head * 128);
      const float* gv   = set ? (isq ? gq2 : gk2) : (isq ? gq : gk);
      __bf16* dst       = set ? (isq ? Q1 : K1) : (isq ? Q0 : K0);
      const int nheads  = isq ? H_ : HKV_;
      const size_t didx = (((size_t)b * nheads + head) * S_ + s) * D_;
      float x1 = (float)src[lane], x2 = (float)src[lane + 64];
      float ss = x1 * x1 + x2 * x2;
#pragma unroll
      for (int o = 1; o < 64; o <<= 1) ss += __shfl_xor(ss, o);
      const float rr = rsqrtf(ss * (1.f / 128.f) + 1e-6f);
      const float n1 = x1 * rr * gv[lane];
      const float n2 = x2 * rr * gv[lane + 64];
      dst[didx + lane]      = (__bf16)(n1 * c1 - n2 * s1);
      dst[didx + lane + 64] = (__bf16)(n2 * c2 + n1 * s2);
    }
  } else {
    const int bid = blockIdx.x - 2048;
    const int st = bid & 15;
    const int hk = (bid >> 4) & 7;
    const int b  = (bid >> 7) & 1;
    const int sg = bid >> 8;
    const int s0 = st * 64;
    const size_t prow = ((size_t)(b * S_ + s0)) * NPROJ + sg * 4096 + 3072 + hk * 128;
    const int r = tid >> 4, c = (tid & 15) * 8;
#pragma unroll
    for (int pass = 0; pass < 4; ++pass) {
      const int rr = pass * 16 + r;
      *(bf16x8*)&T[rr][c] = *(const bf16x8*)&proj[prow + (size_t)rr * NPROJ + c];
    }
    __syncthreads();
    __bf16* Vt = (sg ? Vt1 : Vt0) + (size_t)(b * HKV_ + hk) * D_ * S_;
    const int d = tid >> 1, half = tid & 1;
#pragma unroll
    for (int q8 = 0; q8 < 4; ++q8) {
      const int sb = half * 32 + q8 * 8;
      bf16x8 v;
#pragma unroll
      for (int k = 0; k < 8; ++k) v[k] = T[sb + k][d];
      *(bf16x8*)&Vt[(size_t)d * S_ + s0 + sb] = v;
    }
  }
}

// ---------------------------------------------------------------- fused two-stream windowed attention
// SINGLES: block = one (b,h,qt), grid 512, heavy-first (qt=15 dispatched first) -> LPT packing;
// 69KB LDS x 2 = 138KB <= 160KB -> 2 blocks/CU co-resident (m114 cross-block latency hiding).
// Fixed-max softmax (no max-reduce/rescale), per-lane partial denominators, 1 reduce at end.
__global__ __launch_bounds__(256) void attn_fused(
    const __bf16* __restrict__ Q0, const __bf16* __restrict__ K0g, const __bf16* __restrict__ Vt0,
    const __bf16* __restrict__ Q1, const __bf16* __restrict__ K1g, const __bf16* __restrict__ Vt1,
    __bf16* __restrict__ AO) {
  __shared__ __bf16 KsL[2][2][32 * 128];
  __shared__ __bf16 VtL[2][2][128 * 32];
  __shared__ __bf16 Ps[4][16][40];

  const int tid = threadIdx.x, lane = tid & 63, wid = tid >> 6;
  const int bid = blockIdx.x;
  const int xcd = bid & 7, iidx = bid >> 3;      // iidx 0..63
  const int bh = xcd * 4 + (iidx & 3);           // XCD-pinned heads
  const int qt = 15 - (iidx >> 2);               // heavy-first
  const int b = bh >> 4, h = bh & 15, hk = h >> 1;
  const int qb = qt * 64;
  const int qw = qb + wid * 16;
  const int nt = 2 * qt + 2;

  const int g = lane >> 4, kc = lane & 15;
  const size_t qoff  = (size_t)(b * H_ + h) * S_ * D_;
  const size_t koff  = (size_t)(b * HKV_ + hk) * S_ * D_;
  const size_t vtoff = (size_t)(b * HKV_ + hk) * D_ * S_;

  int kRow[2], kCol[2], vD[2], vJ[2];
#pragma unroll
  for (int p = 0; p < 2; ++p) {
    const int boff = (wid * 2 + p) * 1024 + lane * 16;
    kRow[p] = boff >> 8;
    kCol[p] = ((boff & 255) ^ ((kRow[p] & 7) << 4)) >> 1;
    vD[p]   = boff >> 6;
    vJ[p]   = (boff & 63) >> 1;
  }

  bf16x8 qf0[4], qf1[4];
  {
    const int qrow = qw + kc;
#pragma unroll
    for (int c = 0; c < 4; ++c) {
      qf0[c] = *(const bf16x8*)&Q0[qoff + (size_t)qrow * D_ + c * 32 + g * 8];
      qf1[c] = *(const bf16x8*)&Q1[qoff + (size_t)qrow * D_ + c * 32 + g * 8];
    }
  }

  float rs[4] = {0.f, 0.f, 0.f, 0.f};
  f32x4 o[8] = {};

  auto stage = [&](int t, int bufi) {
    const int j0 = t * 32;
    const bool nic = (j0 >= qb - 286);
    const bool nf  = (j0 <= qb - 193);
#pragma unroll
    for (int p = 0; p < 2; ++p) {
      const int ko = wid * 2048 + p * 1024;
      if (nic) {
        gload16(K0g + koff + (size_t)(j0 + kRow[p]) * D_ + kCol[p], (char*)&KsL[bufi][0][0] + ko);
        gload16(Vt0 + vtoff + (size_t)vD[p] * S_ + j0 + vJ[p],      (char*)&VtL[bufi][0][0] + ko);
      }
      if (nf) {
        gload16(K1g + koff + (size_t)(j0 + kRow[p]) * D_ + kCol[p], (char*)&KsL[bufi][1][0] + ko);
        gload16(Vt1 + vtoff + (size_t)vD[p] * S_ + j0 + vJ[p],      (char*)&VtL[bufi][1][0] + ko);
      }
    }
  };

  auto qk = [&](const __bf16* Kb, const bf16x8 qf[4], f32x4 sv[2]) {
#pragma unroll
    for (int c = 0; c < 4; ++c) {
      const int r0 = kc, r1 = kc + 16;
      const bf16x8 k0f = *(const bf16x8*)((const char*)Kb + r0 * 256 + ((c * 64 + g * 16) ^ ((r0 & 7) << 4)));
      const bf16x8 k1f = *(const bf16x8*)((const char*)Kb + r1 * 256 + ((c * 64 + g * 16) ^ ((r1 & 7) << 4)));
      sv[0] = __builtin_amdgcn_mfma_f32_16x16x32_bf16(qf[c], k0f, sv[0], 0, 0, 0);
      sv[1] = __builtin_amdgcn_mfma_f32_16x16x32_bf16(qf[c], k1f, sv[1], 0, 0, 0);
    }
  };

  auto dopv = [&](const f32x4 sv[2], const __bf16* Vtb) {
#pragma unroll
    for (int nh = 0; nh < 2; ++nh) {
      const int col = kc + nh * 16, c8 = col >> 3, cw = col & 7;
#pragma unroll
      for (int r = 0; r < 4; ++r)
        Ps[wid][g * 4 + r][((c8 ^ g) << 3) + cw] = (__bf16)sv[nh][r];
    }
    asm volatile("s_waitcnt lgkmcnt(0)" ::: "memory");
    const bf16x8 pa = *(const bf16x8*)&Ps[wid][kc][(g ^ (kc >> 2)) << 3];
#pragma unroll
    for (int ch = 0; ch < 8; ++ch) {
      const bf16x8 vb = *(const bf16x8*)&Vtb[(ch * 16 + kc) * 32 + g * 8];
      o[ch] = __builtin_amdgcn_mfma_f32_16x16x32_bf16(pa, vb, o[ch], 0, 0, 0);
    }
  };

  stage(0, 0);
  asm volatile("s_waitcnt vmcnt(0)" ::: "memory");
  __builtin_amdgcn_s_barrier();
  int cur = 0;

  for (int t = 0; t < nt; ++t) {
    if (t + 1 < nt) stage(t + 1, cur ^ 1);
    const int j0 = t * 32;
    if (j0 <= qw + 15) {
      const bool w_ic = (j0 >= qw - 286);
      const bool w_f  = (j0 <= qw - 241);

      f32x4 sic[2] = {}, sfd[2] = {};
      if (w_ic) {
        qk(&KsL[cur][0][0], qf0, sic);
#pragma unroll
        for (int nh = 0; nh < 2; ++nh)
#pragma unroll
          for (int r = 0; r < 4; ++r) {
            const int dij = (qw + g * 4 + r) - (j0 + kc + nh * 16);
            const float arg = (dij >= 0 && dij < W_) ? fmaf(sic[nh][r], SCALE_, -FIXM) : MNEG;
            const float p = __expf(arg);
            rs[r] += p; sic[nh][r] = p;
          }
        dopv(sic, &VtL[cur][0][0]);
      }
      if (w_f) {
        qk(&KsL[cur][1][0], qf1, sfd);
#pragma unroll
        for (int nh = 0; nh < 2; ++nh)
#pragma unroll
          for (int r = 0; r < 4; ++r) {
            const int dij = (qw + g * 4 + r) - (j0 + kc + nh * 16);
            const float arg = (dij >= W_) ? fmaf(sfd[nh][r], SCALE_, -FIXM) : MNEG;
            const float p = __expf(arg);
            rs[r] += p; sfd[nh][r] = p;
          }
        dopv(sfd, &VtL[cur][1][0]);
      }
    }
    asm volatile("s_waitcnt vmcnt(0)" ::: "memory");
    __builtin_amdgcn_s_barrier();
    cur ^= 1;
  }

  // epilogue: reduce per-lane partial denominators once, normalize, store
  float ell[4];
#pragma unroll
  for (int r = 0; r < 4; ++r) ell[r] = rs[r];
#pragma unroll
  for (int ofs = 1; ofs < 16; ofs <<= 1)
#pragma unroll
    for (int r = 0; r < 4; ++r) ell[r] += __shfl_xor(ell[r], ofs);
#pragma unroll
  for (int r = 0; r < 4; ++r) {
    const float inv = 1.f / ell[r];
    const size_t orow = ((size_t)b * S_ + qw + g * 4 + r) * (size_t)(H_ * D_) + h * D_;
#pragma unroll
    for (int ch = 0; ch < 8; ++ch)
      AO[orow + ch * 16 + kc] = (__bf16)(o[ch][r] * inv);
  }
}

// ---------------------------------------------------------------- launch
extern "C" void kernel_launch(void* const* d_in, const int* in_sizes, int n_in,
                              void* d_out, int out_size, void* d_ws, size_t ws_size,
                              hipStream_t stream) {
  (void)in_sizes; (void)n_in; (void)out_size; (void)ws_size;
  const float* hidden = (const float*)d_in[0];
  const float* cosg   = (const float*)d_in[1];
  const float* sing   = (const float*)d_in[2];
  const float* Wq  = (const float*)d_in[3];
  const float* bq  = (const float*)d_in[4];
  const float* Wk  = (const float*)d_in[5];
  const float* bk  = (const float*)d_in[6];
  const float* Wv  = (const float*)d_in[7];
  const float* bv  = (const float*)d_in[8];
  const float* Wq2 = (const float*)d_in[9];
  const float* bq2 = (const float*)d_in[10];
  const float* Wk2 = (const float*)d_in[11];
  const float* bk2 = (const float*)d_in[12];
  const float* Wv2 = (const float*)d_in[13];
  const float* bv2 = (const float*)d_in[14];
  const float* Wo  = (const float*)d_in[15];
  const float* gq  = (const float*)d_in[16];
  const float* gk  = (const float*)d_in[17];
  const float* gq2 = (const float*)d_in[18];
  const float* gk2 = (const float*)d_in[19];

  // ws layout (bytes): [Xb 8M | Wall 32M | Wob 8M | bias 32K | proj 32M]
  char* w = (char*)d_ws;
  __bf16* Xb    = (__bf16*)(w);
  __bf16* Wall  = (__bf16*)(w + 8388608);
  __bf16* Wob   = (__bf16*)(w + 41943040);
  float*  biasA = (float*) (w + 50331648);
  __bf16* proj  = (__bf16*)(w + 50364416);
  // region reuse after gemm_qkv consumed Xb/Wall:
  __bf16* AO  = Xb;
  __bf16* Q0  = Wall;
  __bf16* Q1  = Wall + 4194304;
  __bf16* K0  = Wall + 8388608;
  __bf16* K1  = Wall + 10485760;
  __bf16* Vt0 = Wall + 12582912;
  __bf16* Vt1 = Wall + 14680064;

  cvt_all<<<24584, 256, 0, stream>>>(hidden, Wq, Wk, Wv, Wq2, Wk2, Wv2, Wo,
                                     bq, bk, bv, bq2, bk2, bv2,
                                     Xb, Wall, Wob, biasA);
  gemm_qkv<<<256, 512, 0, stream>>>(Xb, Wall, proj, biasA, NPROJ, DM_, 4);
  post_all<<<2560, 256, 0, stream>>>(proj, cosg, sing, gq, gk, gq2, gk2,
                                     Q0, K0, Q1, K1, Vt0, Vt1);
  attn_fused<<<512, 256, 0, stream>>>(Q0, K0, Vt0, Q1, K1, Vt1, AO);
  gemm_out<<<256, 512, 0, stream>>>(AO, Wob, (float*)d_out);
}